// Round 9
// baseline (186.267 us; speedup 1.0000x reference)
//
#include <hip/hip_runtime.h>

typedef _Float16 f16x8 __attribute__((ext_vector_type(8)));
typedef _Float16 f16x4 __attribute__((ext_vector_type(4)));
typedef float f32x4 __attribute__((ext_vector_type(4)));

#define T_DIM 2048
#define E_DIM 2048
#define D_DIM 128
#define NB 4
#define KSP_P 4    // proj K-splits (K=2048 -> 512 each)
#define KCH_P 512
#define KSP_A 8    // av K-splits (chunks of 256 over s)
#define KCH_A 256
#define NCH2 32    // stats chunks of 64 t-rows
#define ST_LD 136  // s_gemm transpose tile leading dim

__device__ __forceinline__ void gll16(const void* g, void* l) {
  __builtin_amdgcn_global_load_lds(
      (const __attribute__((address_space(1))) unsigned int*)g,
      (__attribute__((address_space(3))) unsigned int*)l, 16, 0, 0);
}

__device__ __forceinline__ void merge_stat(float& m, float& l, float pm, float pl) {
  if (pm != -__builtin_inff()) {
    float nm = fmaxf(m, pm);
    l = l * __expf(m - nm) + pl * __expf(pm - nm);
    m = nm;
  }
}

// ---------------- W [E,D] fp32 -> WhT [D,E] fp16 (B^T layout), 3 matrices ----------------

__global__ void cvt_w(const float* __restrict__ Wq, const float* __restrict__ Wk,
                      const float* __restrict__ Wv, _Float16* __restrict__ WhT) {
  int idx = blockIdx.x * 256 + threadIdx.x;  // 0..262143
  int w = blockIdx.y;
  const float* W = (w == 0) ? Wq : ((w == 1) ? Wk : Wv);
  int e = idx & (E_DIM - 1), d = idx >> 11;
  WhT[(size_t)w * (D_DIM * E_DIM) + idx] = (_Float16)W[e * D_DIM + d];
}

// ---------------- projection GEMM: 128x128, split-K x4, BK=32, fp16 A + reg-prefetch ----
// Software pipeline, 1 barrier/iter:
//   barrier -> ds_write A(k+1) [regs loaded last iter] -> DMA B(k+1) -> load A(k+2) -> MFMA(k)
// All VM ops get a full MFMA phase before the next barrier's vmcnt(0) drain.
// LDS/iter: A 8KB wr + B 8KB wr + 32KB rd (was 72KB with fp32 A staging).
// XOR-seg swizzle f(row)=(row>>1)&3 on both tiles (2-way reads = free).

__global__ __launch_bounds__(256) void proj_gemm(
    const float* __restrict__ x, const _Float16* __restrict__ WhT,
    _Float16* __restrict__ Ph) {
  __shared__ _Float16 Asw[2][128 * 32];  // 2 x 8 KB fp16, swizzled
  __shared__ _Float16 Bsw[2][128 * 32];  // 2 x 8 KB fp16, swizzled
  const int tid = threadIdx.x, w = tid >> 6, lane = tid & 63;
  const int wr = w >> 1, wc = w & 1, quad = lane >> 4, l16 = lane & 15;
  const int t0 = blockIdx.x * 128;
  const int wsel = blockIdx.y, ks = blockIdx.z;
  const _Float16* B = WhT + (size_t)wsel * (D_DIM * E_DIM);
  const int arow0 = tid >> 2, aseg = tid & 3;  // A: 2 passes of 64 rows
  const int brow = tid >> 2, bseg = tid & 3;   // B: 2 passes of 64 rows (DMA)
  const int kstart = ks * KCH_P, kend = kstart + KCH_P;

  f32x4 pa[2][2];  // prefetched A fp32: [pass][half]

#define LOADA(kk)                                                         \
  do {                                                                    \
    _Pragma("unroll") for (int p = 0; p < 2; ++p) {                       \
      int row = p * 64 + arow0;                                           \
      const float* xp = x + (size_t)(t0 + row) * E_DIM + (kk) + aseg * 8; \
      pa[p][0] = *(const f32x4*)xp;                                       \
      pa[p][1] = *(const f32x4*)(xp + 4);                                 \
    }                                                                     \
  } while (0)

#define WRITEA(bufi)                                                      \
  do {                                                                    \
    _Pragma("unroll") for (int p = 0; p < 2; ++p) {                       \
      int row = p * 64 + arow0;                                           \
      f16x8 o;                                                            \
      _Pragma("unroll") for (int e = 0; e < 4; ++e) {                     \
        o[e] = (_Float16)pa[p][0][e];                                     \
        o[e + 4] = (_Float16)pa[p][1][e];                                 \
      }                                                                   \
      int sg = aseg ^ ((row >> 1) & 3);                                   \
      *(f16x8*)(Asw[bufi] + row * 32 + sg * 8) = o;                       \
    }                                                                     \
  } while (0)

#define DMAB(bufi, kk)                                                    \
  do {                                                                    \
    _Pragma("unroll") for (int p = 0; p < 2; ++p) {                       \
      int row = p * 64 + brow;                                            \
      int gseg = bseg ^ ((row >> 1) & 3);                                 \
      gll16(B + (size_t)row * E_DIM + (kk) + gseg * 8,                    \
            Bsw[bufi] + row * 32 + bseg * 8);                             \
    }                                                                     \
  } while (0)

  LOADA(kstart);
  WRITEA(0);
  DMAB(0, kstart);
  LOADA(kstart + 32);
  f32x4 acc[4][4] = {};
  int buf = 0;
  for (int k0 = kstart; k0 < kend; k0 += 32) {
    __syncthreads();  // drains B-DMA(buf) + A-loads; syncs buf^1 readers
    if (k0 + 32 < kend) {
      WRITEA(buf ^ 1);
      DMAB(buf ^ 1, k0 + 32);
      if (k0 + 64 < kend) LOADA(k0 + 64);
    }
    f16x8 af[4], bf[4];
#pragma unroll
    for (int i = 0; i < 4; ++i) {
      int row = wr * 64 + i * 16 + l16;
      int sg = quad ^ ((row >> 1) & 3);
      af[i] = *(const f16x8*)(Asw[buf] + row * 32 + sg * 8);
    }
#pragma unroll
    for (int j = 0; j < 4; ++j) {
      int row = wc * 64 + j * 16 + l16;
      int sg = quad ^ ((row >> 1) & 3);
      bf[j] = *(const f16x8*)(Bsw[buf] + row * 32 + sg * 8);
    }
#pragma unroll
    for (int i = 0; i < 4; ++i)
#pragma unroll
      for (int j = 0; j < 4; ++j)
        acc[i][j] = __builtin_amdgcn_mfma_f32_16x16x32_f16(af[i], bf[j], acc[i][j], 0, 0, 0);
    buf ^= 1;
  }
#undef LOADA
#undef WRITEA
#undef DMAB
  _Float16* P = Ph + ((size_t)(ks * 3 + wsel) << 20);
  if (wsel < 2) {
#pragma unroll
    for (int i = 0; i < 4; ++i)
#pragma unroll
      for (int j = 0; j < 4; ++j) {
        int n = wc * 64 + j * 16 + l16;
#pragma unroll
        for (int r = 0; r < 4; ++r) {
          int t = t0 + wr * 64 + i * 16 + quad * 4 + r;
          P[(size_t)t * D_DIM + n] = (_Float16)acc[i][j][r];
        }
      }
  } else {
    // V: pre-transposed partial, 4 consecutive t at fixed n -> f16x4 store
#pragma unroll
    for (int i = 0; i < 4; ++i)
#pragma unroll
      for (int j = 0; j < 4; ++j) {
        int n = wc * 64 + j * 16 + l16;
        int t = t0 + wr * 64 + i * 16 + quad * 4;
        f16x4 o;
#pragma unroll
        for (int r = 0; r < 4; ++r) o[r] = (_Float16)acc[i][j][r];
        *(f16x4*)(P + ((size_t)(t >> 11) * D_DIM + n) * T_DIM + (t & (T_DIM - 1))) = o;
      }
  }
}

// ---------------- reduce proj partials (4 slots) -> Qh, Kh, VT ----------------

__global__ void proj_reduce(const _Float16* __restrict__ Ph, _Float16* __restrict__ Qh,
                            _Float16* __restrict__ Kh, _Float16* __restrict__ VT) {
  size_t u = ((size_t)blockIdx.x * 256 + threadIdx.x) * 8;
  int mat = (int)(u >> 20);
  size_t rem = u & ((1u << 20) - 1);
  float s[8] = {};
#pragma unroll
  for (int ks = 0; ks < KSP_P; ++ks) {
    f16x8 p = *(const f16x8*)(Ph + ((size_t)(ks * 3 + mat) << 20) + rem);
#pragma unroll
    for (int e = 0; e < 8; ++e) s[e] += (float)p[e];
  }
  f16x8 o;
#pragma unroll
  for (int e = 0; e < 8; ++e) o[e] = (_Float16)s[e];
  _Float16* dst = (mat == 0) ? Qh : ((mat == 1) ? Kh : VT);
  *(f16x8*)(dst + rem) = o;
}

// ---------------- S = Q K^T / sqrt(D), single-barrier full-K + fused stats ----------------

__global__ __launch_bounds__(256) void s_gemm(const _Float16* __restrict__ Qh,
                                              const _Float16* __restrict__ Kh,
                                              _Float16* __restrict__ S,
                                              float* __restrict__ Pm,
                                              float* __restrict__ Pl) {
  // triangular decode
  int idx = blockIdx.x;
  int xt = (int)((sqrtf(8.f * idx + 1.f) - 1.f) * 0.5f);
  while ((xt + 1) * (xt + 2) / 2 <= idx) ++xt;
  while (xt * (xt + 1) / 2 > idx) --xt;
  int yt = idx - xt * (xt + 1) / 2;
  // smem: B staging (32 KB) then reused as 128x136 transpose tile
  __shared__ __align__(16) char smem[128 * ST_LD * 2];  // 34816 B
  _Float16* Bs = (_Float16*)smem;
  _Float16* St = (_Float16*)smem;
  const int tid = threadIdx.x, w = tid >> 6, lane = tid & 63;
  const int wr = w >> 1, wc = w & 1, quad = lane >> 4, l16 = lane & 15;
  const int t0 = xt * 128, s0 = yt * 128, b = blockIdx.y;
  const _Float16* A = Qh + (size_t)b * T_DIM * D_DIM;
  const _Float16* B = Kh + (size_t)b * T_DIM * D_DIM;
  const int srow = lane >> 2;
  const int swz = ((lane & 3) ^ ((srow >> 1) & 3)) * 8;  // source-col swizzle
#pragma unroll
  for (int kq = 0; kq < 4; ++kq)
#pragma unroll
    for (int q = 0; q < 2; ++q) {
      int rbase = w * 32 + q * 16;
      gll16(B + (size_t)(s0 + rbase + srow) * D_DIM + kq * 32 + swz,
            Bs + kq * 4096 + rbase * 32);
    }
  __syncthreads();
  f32x4 acc[4][4] = {};
  const int bsg = (quad ^ ((l16 >> 1) & 3)) * 8;
#pragma unroll
  for (int kq = 0; kq < 4; ++kq) {
    f16x8 af[4], bf[4];
#pragma unroll
    for (int i = 0; i < 4; ++i)
      af[i] = *(const f16x8*)(A + (size_t)(t0 + wr * 64 + i * 16 + l16) * D_DIM +
                              kq * 32 + quad * 8);
#pragma unroll
    for (int j = 0; j < 4; ++j)
      bf[j] = *(const f16x8*)(Bs + kq * 4096 + (wc * 64 + j * 16 + l16) * 32 + bsg);
#pragma unroll
    for (int i = 0; i < 4; ++i)
#pragma unroll
      for (int j = 0; j < 4; ++j)
        acc[i][j] = __builtin_amdgcn_mfma_f32_16x16x32_f16(af[i], bf[j], acc[i][j], 0, 0, 0);
  }
  const float scale = 0.08838834764831845f;  // 1/sqrt(128)
  const float NEG = -__builtin_inff();
  __syncthreads();  // all waves done reading Bs; safe to reuse as St
#pragma unroll
  for (int j = 0; j < 4; ++j) {
    const int s = s0 + wc * 64 + j * 16 + l16;
    const int sloc = wc * 64 + j * 16 + l16;
    float m = NEG;
#pragma unroll
    for (int i = 0; i < 4; ++i)
#pragma unroll
      for (int r = 0; r < 4; ++r) {
        int tloc = wr * 64 + i * 16 + quad * 4 + r;
        float v = (s > t0 + tloc) ? NEG : acc[i][j][r] * scale;
        St[tloc * ST_LD + sloc] = (_Float16)v;
        m = fmaxf(m, v);
      }
    float l = 0.f;
    if (m != NEG) {
#pragma unroll
      for (int i = 0; i < 4; ++i)
#pragma unroll
        for (int r = 0; r < 4; ++r) {
          int tloc = wr * 64 + i * 16 + quad * 4 + r;
          float v = (s > t0 + tloc) ? NEG : acc[i][j][r] * scale;
          l += __expf(v - m);  // exp(-inf - m) = 0
        }
    }
    // merge across quad dim (lanes xor 16, 32)
#pragma unroll
    for (int d = 16; d <= 32; d <<= 1) {
      float pm = __shfl_xor(m, d, 64);
      float pl = __shfl_xor(l, d, 64);
      merge_stat(m, l, pm, pl);
    }
    if (quad == 0) {
      int c = 2 * xt + wr;
      Pm[((size_t)c * NB + b) * T_DIM + s] = m;
      Pl[((size_t)c * NB + b) * T_DIM + s] = l;
    }
  }
  __syncthreads();
  // coalesced store: each thread handles one row-half (64 cols = 8 x f16x8)
  _Float16* Sb = S + (size_t)b * T_DIM * T_DIM;
  const int rr = tid >> 1, hh = tid & 1;
#pragma unroll
  for (int e = 0; e < 8; ++e) {
    f16x8 v = *(const f16x8*)(St + rr * ST_LD + hh * 64 + e * 8);
    *(f16x8*)(Sb + (size_t)(t0 + rr) * T_DIM + s0 + hh * 64 + e * 8) = v;
  }
}

// ---------------- Z = A V, split-K, stats-merge fused: grid (16, 4, KSP_A) ----------------
// Prologue: thread tid merges column (Kstart+tid)'s Pm/Pl chunks -> Ms/Ls in LDS.

__global__ __launch_bounds__(256) void av_gemm(const _Float16* __restrict__ S,
                                               const _Float16* __restrict__ VT,
                                               const float* __restrict__ Pm,
                                               const float* __restrict__ Pl,
                                               float* __restrict__ Zp) {
  const int t0 = blockIdx.x * 128, b = blockIdx.y, ks = blockIdx.z;
  const int Kmax = t0 + 128;
  const int Kstart = ks * KCH_A;
  if (Kstart >= Kmax) return;
  const int Kend = (Kstart + KCH_A < Kmax) ? (Kstart + KCH_A) : Kmax;
  __shared__ _Float16 As[128 * 32];
  __shared__ _Float16 Bs[128 * 32];
  __shared__ float Ms[KCH_A];
  __shared__ float Ls[KCH_A];
  const int tid = threadIdx.x, w = tid >> 6, lane = tid & 63;
  const int wr = w >> 1, wc = w & 1, quad = lane >> 4, l16 = lane & 15;
  const _Float16* Sb = S + (size_t)b * T_DIM * T_DIM;
  const _Float16* Vb = VT + (size_t)b * D_DIM * T_DIM;
  {
    // per-column softmax stats: merge partial chunks >= s>>6 (diag chunk first)
    int s = Kstart + tid;
    float m = -__builtin_inff(), l = 0.f;
    for (int ch = s >> 6; ch < NCH2; ++ch) {
      size_t pidx = ((size_t)ch * NB + b) * T_DIM + s;
      merge_stat(m, l, Pm[pidx], Pl[pidx]);
    }
    Ms[tid] = m;
    Ls[tid] = 1.f / l;
  }
  const int srow = lane >> 2, scol = (lane & 3) * 8;
  f32x4 acc[4][4] = {};
  for (int k0 = Kstart; k0 < Kend; k0 += 32) {
    __syncthreads();
#pragma unroll
    for (int q = 0; q < 2; ++q) {
      // A tile: load S fp16, apply a = exp(s - m_col) * inv_l_col, write LDS
      int u = q * 256 + tid;
      int row = u >> 2, c8 = (u & 3) * 8;
      int sc = k0 + c8;
      f16x8 v = *(const f16x8*)(Sb + (size_t)(t0 + row) * T_DIM + sc);
      f16x8 o;
#pragma unroll
      for (int e = 0; e < 8; ++e) {
        int li = sc + e - Kstart;
        float a = __expf((float)v[e] - Ms[li]) * Ls[li];
        o[e] = (_Float16)a;
      }
      *(f16x8*)(As + row * 32 + c8) = o;
      // B tile: V^T rows (d-major), direct-to-LDS
      int rbase = w * 32 + q * 16;
      gll16(Vb + (size_t)(rbase + srow) * T_DIM + k0 + scol, Bs + rbase * 32);
    }
    __syncthreads();
    f16x8 af[4], bf[4];
#pragma unroll
    for (int i = 0; i < 4; ++i)
      af[i] = *(const f16x8*)(As + (wr * 64 + i * 16 + l16) * 32 + quad * 8);
#pragma unroll
    for (int j = 0; j < 4; ++j)
      bf[j] = *(const f16x8*)(Bs + (wc * 64 + j * 16 + l16) * 32 + quad * 8);
#pragma unroll
    for (int i = 0; i < 4; ++i)
#pragma unroll
      for (int j = 0; j < 4; ++j)
        acc[i][j] = __builtin_amdgcn_mfma_f32_16x16x32_f16(af[i], bf[j], acc[i][j], 0, 0, 0);
  }
  float* Zb = Zp + ((size_t)ks * NB + b) * T_DIM * D_DIM;
#pragma unroll
  for (int i = 0; i < 4; ++i)
#pragma unroll
    for (int j = 0; j < 4; ++j) {
      int n = wc * 64 + j * 16 + l16;
#pragma unroll
      for (int r = 0; r < 4; ++r) {
        int t = t0 + wr * 64 + i * 16 + quad * 4 + r;
        Zb[(size_t)t * D_DIM + n] = acc[i][j][r];
      }
    }
}

// ---------------- reduce Z partials -> output ----------------

__global__ void z_reduce(const float* __restrict__ Zp, float* __restrict__ Z) {
  size_t flat = ((size_t)blockIdx.x * 256 + threadIdx.x) * 4;
  int t = (int)((flat >> 7) & (T_DIM - 1));
  int ns = ((t >> 7) + 2) >> 1;  // ceil((x+1)/2), x = t/128
  f32x4 s = {};
  for (int ks = 0; ks < ns; ++ks) {
    f32x4 p = *(const f32x4*)(Zp + ((size_t)ks * NB * T_DIM * D_DIM) + flat);
    s += p;
  }
  *(f32x4*)(Z + flat) = s;
}

// ---------------- launch ----------------

extern "C" void kernel_launch(void* const* d_in, const int* in_sizes, int n_in,
                              void* d_out, int out_size, void* d_ws, size_t ws_size,
                              hipStream_t stream) {
  const float* x = (const float*)d_in[0];
  const float* Wq = (const float*)d_in[1];
  const float* Wk = (const float*)d_in[2];
  const float* Wv = (const float*)d_in[3];
  char* ws = (char*)d_ws;
  // workspace layout (~79 MB), aliasing:
  //  [0, 33.5MB): Zp (av partials; region idle during proj/s phases)
  //  [41.4MB, 74.9MB): Ph during proj; overwritten by S after proj_reduce
  float* Zp = (float*)(ws);                                // 33,554,432 B
  _Float16* WhT = (_Float16*)(ws + 33554432);              //  1,572,864 B
  _Float16* Qh = (_Float16*)(ws + 35127296);               //  2,097,152 B
  _Float16* Kh = (_Float16*)(ws + 37224448);               //  2,097,152 B
  _Float16* VT = (_Float16*)(ws + 39321600);               //  2,097,152 B
  _Float16* S = (_Float16*)(ws + 41418752);                // 33,554,432 B
  _Float16* Ph = (_Float16*)(ws + 41418752);               // 25,165,824 B (alias S)
  float* Pm = (float*)(ws + 75038720);                     //  1,048,576 B
  float* Pl = (float*)(ws + 76087296);                     //  1,048,576 B
  float* Z = (float*)d_out;

  cvt_w<<<dim3(1024, 3), 256, 0, stream>>>(Wq, Wk, Wv, WhT);
  proj_gemm<<<dim3(64, 3, KSP_P), 256, 0, stream>>>(x, WhT, Ph);
  proj_reduce<<<1536, 256, 0, stream>>>(Ph, Qh, Kh, VT);
  s_gemm<<<dim3(136, 4), 256, 0, stream>>>(Qh, Kh, S, Pm, Pl);
  av_gemm<<<dim3(16, 4, KSP_A), 256, 0, stream>>>(S, VT, Pm, Pl, Zp);
  z_reduce<<<1024, 256, 0, stream>>>(Zp, Z);
}

// Round 10
// 176.739 us; speedup vs baseline: 1.0539x; 1.0539x over previous
//
#include <hip/hip_runtime.h>

typedef _Float16 f16x8 __attribute__((ext_vector_type(8)));
typedef _Float16 f16x4 __attribute__((ext_vector_type(4)));
typedef float f32x4 __attribute__((ext_vector_type(4)));

#define T_DIM 2048
#define E_DIM 2048
#define D_DIM 128
#define NB 4
#define KSP_P 4    // proj K-splits (K=2048 -> 512 each)
#define KCH_P 512
#define KSP_A 8    // av K-splits (chunks of 256 over s)
#define KCH_A 256
#define NCH2 32    // stats chunks of 64 t-rows
#define ST_LD 136  // s_gemm transpose tile leading dim

__device__ __forceinline__ void gll16(const void* g, void* l) {
  __builtin_amdgcn_global_load_lds(
      (const __attribute__((address_space(1))) unsigned int*)g,
      (__attribute__((address_space(3))) unsigned int*)l, 16, 0, 0);
}

__device__ __forceinline__ void merge_stat(float& m, float& l, float pm, float pl) {
  if (pm != -__builtin_inff()) {
    float nm = fmaxf(m, pm);
    l = l * __expf(m - nm) + pl * __expf(pm - nm);
    m = nm;
  }
}

// ---------------- W [E,D] fp32 -> WhT [D,E] fp16 (B^T layout), 3 matrices ----------------

__global__ void cvt_w(const float* __restrict__ Wq, const float* __restrict__ Wk,
                      const float* __restrict__ Wv, _Float16* __restrict__ WhT) {
  int idx = blockIdx.x * 256 + threadIdx.x;  // 0..262143
  int w = blockIdx.y;
  const float* W = (w == 0) ? Wq : ((w == 1) ? Wk : Wv);
  int e = idx & (E_DIM - 1), d = idx >> 11;
  WhT[(size_t)w * (D_DIM * E_DIM) + idx] = (_Float16)W[e * D_DIM + d];
}

// ---------------- fused QKV projection: 128t x 64col x {Q,K,V}, split-K x4 ----------------
// grid (64, 2, KSP_P): x = t-tile, y = col-half of D, z = K-split.
// A (x, fp32) staged ONCE per iter (reg-prefetch pipeline), reused by 3 B-tiles
// -> x global traffic 2x (not 3x... wait per col-half) and A LDS-writes /3,
//    96 MFMA per barrier. XOR-seg swizzle (row>>1)&3 on all tiles (0 conflicts).
// Partials (fp16) to slot ks*3+mat; Q/K row-major, V pre-transposed.

__global__ __launch_bounds__(256) void proj_gemm(
    const float* __restrict__ x, const _Float16* __restrict__ WhT,
    _Float16* __restrict__ Ph) {
  __shared__ _Float16 Asw[2][128 * 32];     // 2 x 8 KB
  __shared__ _Float16 Bsw[2][3][64 * 32];   // 2 x 3 x 4 KB
  const int tid = threadIdx.x, w = tid >> 6, lane = tid & 63;
  const int wr = w >> 1, wc = w & 1, quad = lane >> 4, l16 = lane & 15;
  const int t0 = blockIdx.x * 128;
  const int dh = blockIdx.y, ks = blockIdx.z;
  const int arow0 = tid >> 2, aseg = tid & 3;  // A: 2 passes of 64 rows
  const int brow = tid >> 2, bseg = tid & 3;   // B: 1 pass of 64 rows per mat
  const int kstart = ks * KCH_P, kend = kstart + KCH_P;

  f32x4 pa[2][2];  // prefetched A fp32: [pass][half]

#define LOADA(kk)                                                         \
  do {                                                                    \
    _Pragma("unroll") for (int p = 0; p < 2; ++p) {                       \
      int row = p * 64 + arow0;                                           \
      const float* xp = x + (size_t)(t0 + row) * E_DIM + (kk) + aseg * 8; \
      pa[p][0] = *(const f32x4*)xp;                                       \
      pa[p][1] = *(const f32x4*)(xp + 4);                                 \
    }                                                                     \
  } while (0)

#define WRITEA(bufi)                                                      \
  do {                                                                    \
    _Pragma("unroll") for (int p = 0; p < 2; ++p) {                       \
      int row = p * 64 + arow0;                                           \
      f16x8 o;                                                            \
      _Pragma("unroll") for (int e = 0; e < 4; ++e) {                     \
        o[e] = (_Float16)pa[p][0][e];                                     \
        o[e + 4] = (_Float16)pa[p][1][e];                                 \
      }                                                                   \
      int sg = aseg ^ ((row >> 1) & 3);                                   \
      *(f16x8*)(Asw[bufi] + row * 32 + sg * 8) = o;                       \
    }                                                                     \
  } while (0)

#define DMAB(bufi, kk)                                                    \
  do {                                                                    \
    _Pragma("unroll") for (int m = 0; m < 3; ++m) {                       \
      int gseg = bseg ^ ((brow >> 1) & 3);                                \
      gll16(WhT + (size_t)m * (D_DIM * E_DIM) +                           \
                (size_t)(dh * 64 + brow) * E_DIM + (kk) + gseg * 8,       \
            Bsw[bufi][m] + brow * 32 + bseg * 8);                         \
    }                                                                     \
  } while (0)

  LOADA(kstart);
  WRITEA(0);
  DMAB(0, kstart);
  LOADA(kstart + 32);
  f32x4 acc[3][4][2] = {};
  int buf = 0;
  for (int k0 = kstart; k0 < kend; k0 += 32) {
    __syncthreads();  // drains B-DMA(buf) + A prefetch loads; syncs buf^1 readers
    if (k0 + 32 < kend) {
      WRITEA(buf ^ 1);
      DMAB(buf ^ 1, k0 + 32);
      if (k0 + 64 < kend) LOADA(k0 + 64);
    }
    f16x8 af[4];
#pragma unroll
    for (int i = 0; i < 4; ++i) {
      int row = wr * 64 + i * 16 + l16;
      int sg = quad ^ ((row >> 1) & 3);
      af[i] = *(const f16x8*)(Asw[buf] + row * 32 + sg * 8);
    }
#pragma unroll
    for (int m = 0; m < 3; ++m) {
      f16x8 bf[2];
#pragma unroll
      for (int j = 0; j < 2; ++j) {
        int row = wc * 32 + j * 16 + l16;
        int sg = quad ^ ((row >> 1) & 3);
        bf[j] = *(const f16x8*)(Bsw[buf][m] + row * 32 + sg * 8);
      }
#pragma unroll
      for (int i = 0; i < 4; ++i)
#pragma unroll
        for (int j = 0; j < 2; ++j)
          acc[m][i][j] =
              __builtin_amdgcn_mfma_f32_16x16x32_f16(af[i], bf[j], acc[m][i][j], 0, 0, 0);
    }
    buf ^= 1;
  }
#undef LOADA
#undef WRITEA
#undef DMAB
#pragma unroll
  for (int m = 0; m < 3; ++m) {
    _Float16* P = Ph + ((size_t)(ks * 3 + m) << 20);
    if (m < 2) {
#pragma unroll
      for (int i = 0; i < 4; ++i)
#pragma unroll
        for (int j = 0; j < 2; ++j) {
          int n = dh * 64 + wc * 32 + j * 16 + l16;
#pragma unroll
          for (int r = 0; r < 4; ++r) {
            int t = t0 + wr * 64 + i * 16 + quad * 4 + r;
            P[(size_t)t * D_DIM + n] = (_Float16)acc[m][i][j][r];
          }
        }
    } else {
      // V: pre-transposed partial, 4 consecutive t at fixed n -> f16x4 store
#pragma unroll
      for (int i = 0; i < 4; ++i)
#pragma unroll
        for (int j = 0; j < 2; ++j) {
          int n = dh * 64 + wc * 32 + j * 16 + l16;
          int t = t0 + wr * 64 + i * 16 + quad * 4;
          f16x4 o;
#pragma unroll
          for (int r = 0; r < 4; ++r) o[r] = (_Float16)acc[m][i][j][r];
          *(f16x4*)(P + ((size_t)(t >> 11) * D_DIM + n) * T_DIM + (t & (T_DIM - 1))) = o;
        }
    }
  }
}

// ---------------- reduce proj partials (4 slots) -> Qh, Kh, VT ----------------

__global__ void proj_reduce(const _Float16* __restrict__ Ph, _Float16* __restrict__ Qh,
                            _Float16* __restrict__ Kh, _Float16* __restrict__ VT) {
  size_t u = ((size_t)blockIdx.x * 256 + threadIdx.x) * 8;
  int mat = (int)(u >> 20);
  size_t rem = u & ((1u << 20) - 1);
  float s[8] = {};
#pragma unroll
  for (int ks = 0; ks < KSP_P; ++ks) {
    f16x8 p = *(const f16x8*)(Ph + ((size_t)(ks * 3 + mat) << 20) + rem);
#pragma unroll
    for (int e = 0; e < 8; ++e) s[e] += (float)p[e];
  }
  f16x8 o;
#pragma unroll
  for (int e = 0; e < 8; ++e) o[e] = (_Float16)s[e];
  _Float16* dst = (mat == 0) ? Qh : ((mat == 1) ? Kh : VT);
  *(f16x8*)(dst + rem) = o;
}

// ---------------- S = Q K^T / sqrt(D), single-barrier full-K + fused stats ----------------

__global__ __launch_bounds__(256) void s_gemm(const _Float16* __restrict__ Qh,
                                              const _Float16* __restrict__ Kh,
                                              _Float16* __restrict__ S,
                                              float* __restrict__ Pm,
                                              float* __restrict__ Pl) {
  // triangular decode
  int idx = blockIdx.x;
  int xt = (int)((sqrtf(8.f * idx + 1.f) - 1.f) * 0.5f);
  while ((xt + 1) * (xt + 2) / 2 <= idx) ++xt;
  while (xt * (xt + 1) / 2 > idx) --xt;
  int yt = idx - xt * (xt + 1) / 2;
  // smem: B staging (32 KB) then reused as 128x136 transpose tile
  __shared__ __align__(16) char smem[128 * ST_LD * 2];  // 34816 B
  _Float16* Bs = (_Float16*)smem;
  _Float16* St = (_Float16*)smem;
  const int tid = threadIdx.x, w = tid >> 6, lane = tid & 63;
  const int wr = w >> 1, wc = w & 1, quad = lane >> 4, l16 = lane & 15;
  const int t0 = xt * 128, s0 = yt * 128, b = blockIdx.y;
  const _Float16* A = Qh + (size_t)b * T_DIM * D_DIM;
  const _Float16* B = Kh + (size_t)b * T_DIM * D_DIM;
  const int srow = lane >> 2;
  const int swz = ((lane & 3) ^ ((srow >> 1) & 3)) * 8;  // source-col swizzle
#pragma unroll
  for (int kq = 0; kq < 4; ++kq)
#pragma unroll
    for (int q = 0; q < 2; ++q) {
      int rbase = w * 32 + q * 16;
      gll16(B + (size_t)(s0 + rbase + srow) * D_DIM + kq * 32 + swz,
            Bs + kq * 4096 + rbase * 32);
    }
  __syncthreads();
  f32x4 acc[4][4] = {};
  const int bsg = (quad ^ ((l16 >> 1) & 3)) * 8;
#pragma unroll
  for (int kq = 0; kq < 4; ++kq) {
    f16x8 af[4], bf[4];
#pragma unroll
    for (int i = 0; i < 4; ++i)
      af[i] = *(const f16x8*)(A + (size_t)(t0 + wr * 64 + i * 16 + l16) * D_DIM +
                              kq * 32 + quad * 8);
#pragma unroll
    for (int j = 0; j < 4; ++j)
      bf[j] = *(const f16x8*)(Bs + kq * 4096 + (wc * 64 + j * 16 + l16) * 32 + bsg);
#pragma unroll
    for (int i = 0; i < 4; ++i)
#pragma unroll
      for (int j = 0; j < 4; ++j)
        acc[i][j] = __builtin_amdgcn_mfma_f32_16x16x32_f16(af[i], bf[j], acc[i][j], 0, 0, 0);
  }
  const float scale = 0.08838834764831845f;  // 1/sqrt(128)
  const float NEG = -__builtin_inff();
  __syncthreads();  // all waves done reading Bs; safe to reuse as St
#pragma unroll
  for (int j = 0; j < 4; ++j) {
    const int s = s0 + wc * 64 + j * 16 + l16;
    const int sloc = wc * 64 + j * 16 + l16;
    float m = NEG;
#pragma unroll
    for (int i = 0; i < 4; ++i)
#pragma unroll
      for (int r = 0; r < 4; ++r) {
        int tloc = wr * 64 + i * 16 + quad * 4 + r;
        float v = (s > t0 + tloc) ? NEG : acc[i][j][r] * scale;
        St[tloc * ST_LD + sloc] = (_Float16)v;
        m = fmaxf(m, v);
      }
    float l = 0.f;
    if (m != NEG) {
#pragma unroll
      for (int i = 0; i < 4; ++i)
#pragma unroll
        for (int r = 0; r < 4; ++r) {
          int tloc = wr * 64 + i * 16 + quad * 4 + r;
          float v = (s > t0 + tloc) ? NEG : acc[i][j][r] * scale;
          l += __expf(v - m);  // exp(-inf - m) = 0
        }
    }
    // merge across quad dim (lanes xor 16, 32)
#pragma unroll
    for (int d = 16; d <= 32; d <<= 1) {
      float pm = __shfl_xor(m, d, 64);
      float pl = __shfl_xor(l, d, 64);
      merge_stat(m, l, pm, pl);
    }
    if (quad == 0) {
      int c = 2 * xt + wr;
      Pm[((size_t)c * NB + b) * T_DIM + s] = m;
      Pl[((size_t)c * NB + b) * T_DIM + s] = l;
    }
  }
  __syncthreads();
  // coalesced store: each thread handles one row-half (64 cols = 8 x f16x8)
  _Float16* Sb = S + (size_t)b * T_DIM * T_DIM;
  const int rr = tid >> 1, hh = tid & 1;
#pragma unroll
  for (int e = 0; e < 8; ++e) {
    f16x8 v = *(const f16x8*)(St + rr * ST_LD + hh * 64 + e * 8);
    *(f16x8*)(Sb + (size_t)(t0 + rr) * T_DIM + s0 + hh * 64 + e * 8) = v;
  }
}

// ---------------- combine partials, two-level: 32 chunks of 64 rows ----------------

__global__ __launch_bounds__(256) void comb_stats(const float* __restrict__ Pm,
                                                  const float* __restrict__ Pl,
                                                  float* __restrict__ M,
                                                  float* __restrict__ L) {
  __shared__ float sM[8][32];
  __shared__ float sL[8][32];
  const int g = threadIdx.x >> 5, sl = threadIdx.x & 31;
  const int c = blockIdx.x * 32 + sl;
  const int b = c >> 11, s = c & (T_DIM - 1);
  float m = -__builtin_inff(), l = 0.f;
#pragma unroll
  for (int k = 0; k < NCH2 / 8; ++k) {
    int ch = g * (NCH2 / 8) + k;
    if (ch >= (s >> 6)) {  // chunk intersects valid region (and is written)
      size_t idx = ((size_t)ch * NB + b) * T_DIM + s;
      merge_stat(m, l, Pm[idx], Pl[idx]);
    }
  }
  sM[g][sl] = m;
  sL[g][sl] = l;
  __syncthreads();
  if (threadIdx.x < 32) {
    const int c2 = blockIdx.x * 32 + threadIdx.x;
    float fm = -__builtin_inff(), fl = 0.f;
#pragma unroll
    for (int gg = 0; gg < 8; ++gg) merge_stat(fm, fl, sM[gg][threadIdx.x], sL[gg][threadIdx.x]);
    M[c2] = fm;
    L[c2] = 1.f / fl;
  }
}

// ---------------- Z = A V, split-K: grid (16, 4, KSP_A) ----------------

__global__ __launch_bounds__(256) void av_gemm(const _Float16* __restrict__ S,
                                               const _Float16* __restrict__ VT,
                                               const float* __restrict__ M,
                                               const float* __restrict__ L,
                                               float* __restrict__ Zp) {
  const int t0 = blockIdx.x * 128, b = blockIdx.y, ks = blockIdx.z;
  const int Kmax = t0 + 128;
  const int Kstart = ks * KCH_A;
  if (Kstart >= Kmax) return;
  const int Kend = (Kstart + KCH_A < Kmax) ? (Kstart + KCH_A) : Kmax;
  __shared__ _Float16 As[128 * 32];
  __shared__ _Float16 Bs[128 * 32];
  __shared__ float Ms[KCH_A];
  __shared__ float Ls[KCH_A];
  const int tid = threadIdx.x, w = tid >> 6, lane = tid & 63;
  const int wr = w >> 1, wc = w & 1, quad = lane >> 4, l16 = lane & 15;
  const _Float16* Sb = S + (size_t)b * T_DIM * T_DIM;
  const _Float16* Vb = VT + (size_t)b * D_DIM * T_DIM;
  for (int i = tid; i < Kend - Kstart; i += 256) {
    Ms[i] = M[b * T_DIM + Kstart + i];
    Ls[i] = L[b * T_DIM + Kstart + i];
  }
  const int srow = lane >> 2, scol = (lane & 3) * 8;
  f32x4 acc[4][4] = {};
  for (int k0 = Kstart; k0 < Kend; k0 += 32) {
    __syncthreads();
#pragma unroll
    for (int q = 0; q < 2; ++q) {
      // A tile: load S fp16, apply a = exp(s - m_col) * inv_l_col, write LDS
      int u = q * 256 + tid;
      int row = u >> 2, c8 = (u & 3) * 8;
      int sc = k0 + c8;
      f16x8 v = *(const f16x8*)(Sb + (size_t)(t0 + row) * T_DIM + sc);
      f16x8 o;
#pragma unroll
      for (int e = 0; e < 8; ++e) {
        int li = sc + e - Kstart;
        float a = __expf((float)v[e] - Ms[li]) * Ls[li];
        o[e] = (_Float16)a;
      }
      *(f16x8*)(As + row * 32 + c8) = o;
      // B tile: V^T rows (d-major), direct-to-LDS
      int rbase = w * 32 + q * 16;
      gll16(Vb + (size_t)(rbase + srow) * T_DIM + k0 + scol, Bs + rbase * 32);
    }
    __syncthreads();
    f16x8 af[4], bf[4];
#pragma unroll
    for (int i = 0; i < 4; ++i)
      af[i] = *(const f16x8*)(As + (wr * 64 + i * 16 + l16) * 32 + quad * 8);
#pragma unroll
    for (int j = 0; j < 4; ++j)
      bf[j] = *(const f16x8*)(Bs + (wc * 64 + j * 16 + l16) * 32 + quad * 8);
#pragma unroll
    for (int i = 0; i < 4; ++i)
#pragma unroll
      for (int j = 0; j < 4; ++j)
        acc[i][j] = __builtin_amdgcn_mfma_f32_16x16x32_f16(af[i], bf[j], acc[i][j], 0, 0, 0);
  }
  float* Zb = Zp + ((size_t)ks * NB + b) * T_DIM * D_DIM;
#pragma unroll
  for (int i = 0; i < 4; ++i)
#pragma unroll
    for (int j = 0; j < 4; ++j) {
      int n = wc * 64 + j * 16 + l16;
#pragma unroll
      for (int r = 0; r < 4; ++r) {
        int t = t0 + wr * 64 + i * 16 + quad * 4 + r;
        Zb[(size_t)t * D_DIM + n] = acc[i][j][r];
      }
    }
}

// ---------------- reduce Z partials -> output ----------------

__global__ void z_reduce(const float* __restrict__ Zp, float* __restrict__ Z) {
  size_t flat = ((size_t)blockIdx.x * 256 + threadIdx.x) * 4;
  int t = (int)((flat >> 7) & (T_DIM - 1));
  int ns = ((t >> 7) + 2) >> 1;  // ceil((x+1)/2), x = t/128
  f32x4 s = {};
  for (int ks = 0; ks < ns; ++ks) {
    f32x4 p = *(const f32x4*)(Zp + ((size_t)ks * NB * T_DIM * D_DIM) + flat);
    s += p;
  }
  *(f32x4*)(Z + flat) = s;
}

// ---------------- launch ----------------

extern "C" void kernel_launch(void* const* d_in, const int* in_sizes, int n_in,
                              void* d_out, int out_size, void* d_ws, size_t ws_size,
                              hipStream_t stream) {
  const float* x = (const float*)d_in[0];
  const float* Wq = (const float*)d_in[1];
  const float* Wk = (const float*)d_in[2];
  const float* Wv = (const float*)d_in[3];
  char* ws = (char*)d_ws;
  // workspace layout (~79 MB), aliasing:
  //  [0, 33.5MB): Zp (av partials; region idle during proj/s phases)
  //  [41.4MB, 74.9MB): Ph during proj (12 slots, 24 MB); overwritten by S after
  float* Zp = (float*)(ws);                                // 33,554,432 B
  _Float16* WhT = (_Float16*)(ws + 33554432);              //  1,572,864 B
  _Float16* Qh = (_Float16*)(ws + 35127296);               //  2,097,152 B
  _Float16* Kh = (_Float16*)(ws + 37224448);               //  2,097,152 B
  _Float16* VT = (_Float16*)(ws + 39321600);               //  2,097,152 B
  _Float16* S = (_Float16*)(ws + 41418752);                // 33,554,432 B
  _Float16* Ph = (_Float16*)(ws + 41418752);               // 25,165,824 B (alias S)
  float* M = (float*)(ws + 74973184);                      //     32,768 B
  float* L = (float*)(ws + 75005952);                      //     32,768 B
  float* Pm = (float*)(ws + 75038720);                     //  1,048,576 B
  float* Pl = (float*)(ws + 76087296);                     //  1,048,576 B
  float* Z = (float*)d_out;

  cvt_w<<<dim3(1024, 3), 256, 0, stream>>>(Wq, Wk, Wv, WhT);
  proj_gemm<<<dim3(64, 2, KSP_P), 256, 0, stream>>>(x, WhT, Ph);
  proj_reduce<<<1536, 256, 0, stream>>>(Ph, Qh, Kh, VT);
  s_gemm<<<dim3(136, 4), 256, 0, stream>>>(Qh, Kh, S, Pm, Pl);
  comb_stats<<<256, 256, 0, stream>>>(Pm, Pl, M, L);
  av_gemm<<<dim3(16, 4, KSP_A), 256, 0, stream>>>(S, VT, M, L, Zp);
  z_reduce<<<1024, 256, 0, stream>>>(Zp, Z);
}